// Round 1
// baseline (1098.582 us; speedup 1.0000x reference)
//
#include <hip/hip_runtime.h>
#include <stdint.h>

typedef __attribute__((ext_vector_type(8))) short bf16x8;
typedef __attribute__((ext_vector_type(4))) float f32x4;
typedef unsigned short ushort_t;
typedef unsigned int u32;
typedef const __attribute__((address_space(1))) u32* gp1_t;
typedef __attribute__((address_space(3))) u32* lp3_t;

#define MFMA(a,b,c) __builtin_amdgcn_mfma_f32_16x16x32_bf16((a),(b),(c),0,0,0)

static constexpr int BATCH = 64, LQ = 528, DIM = 768, NH = 12, DH = 64;
static constexpr int MTOK = BATCH * LQ;   // 33792
static constexpr int VTP  = 544;          // padded Vt row stride (keys), mult of 32
static constexpr float SCALE = 0.03608439182435161f; // 768^-0.5

__device__ __forceinline__ ushort_t f2bf(float f) {
  u32 u = __float_as_uint(f);
  u = (u + 0x7fffu + ((u >> 16) & 1u)) >> 16;
  return (ushort_t)u;
}

// ---------------- conversion kernels ----------------
__global__ __launch_bounds__(256) void k_convert_x(const float* __restrict__ x,
                                                   ushort_t* __restrict__ xb) {
  int i = blockIdx.x * 256 + threadIdx.x;     // one float4 per thread, exact grid
  float4 v = ((const float4*)x)[i];
  ushort4 o;
  o.x = f2bf(v.x); o.y = f2bf(v.y); o.z = f2bf(v.z); o.w = f2bf(v.w);
  ((ushort4*)xb)[i] = o;
}

__global__ __launch_bounds__(256) void k_convert_w(
    const float* __restrict__ w0, const float* __restrict__ w1,
    const float* __restrict__ w2, const float* __restrict__ w3,
    ushort_t* __restrict__ o0, ushort_t* __restrict__ o1,
    ushort_t* __restrict__ o2, ushort_t* __restrict__ o3) {
  int i = blockIdx.x * 256 + threadIdx.x;     // 4*768*768 threads, exact grid
  int w = i / (DIM * DIM);
  int rem = i - w * (DIM * DIM);
  int k = rem / DIM;
  int n = rem - k * DIM;
  const float* src = (w == 0) ? w0 : (w == 1) ? w1 : (w == 2) ? w2 : w3;
  ushort_t* dst = (w == 0) ? o0 : (w == 1) ? o1 : (w == 2) ? o2 : o3;
  dst[(size_t)n * DIM + k] = f2bf(src[rem]);  // coalesced read, transposed write
}

// ---------------- B^T GEMM, 128x128 tile, BK=32, m97 structure ----------------
// C[m][n] = sum_k A[m][k] * Bt[n][k], K = 768.
// MODE 0: A=x_bf16 (M=33792 tokens), Bt=W^T (N=768) -> Q/K buffer (B,H,L,64) bf16
// MODE 1: A=Wv^T (M=768 outdim),  Bt=x_bf16 (N=33792 tokens) -> Vt (B,H,64,VTP) bf16
// MODE 2: A=attn out in (B,H,L,64) (M=33792), Bt=Wp^T (N=768) -> fp32 out + bias
template <int MODE>
__global__ __launch_bounds__(256, 2) void k_gemm(const ushort_t* __restrict__ A,
                                                 const ushort_t* __restrict__ Bt,
                                                 void* __restrict__ C,
                                                 const float* __restrict__ bias) {
  __shared__ ushort_t at[128 * 32];
  __shared__ ushort_t bt[128 * 32];
  const int tid = threadIdx.x;
  const int wv = tid >> 6, lane = tid & 63;
  const int lane15 = lane & 15, quad = lane >> 4;
  const int mT = blockIdx.x, nT = blockIdx.y;
  const int mw = (wv & 1) * 64, nw = (wv >> 1) * 64;

  f32x4 acc[4][4];
#pragma unroll
  for (int i = 0; i < 4; i++)
#pragma unroll
    for (int j = 0; j < 4; j++) acc[i][j] = (f32x4)0.0f;

  const int srow = lane >> 2;        // 0..15
  const int sk = (lane & 3) * 8;     // 0,8,16,24 (elements)

  for (int kb = 0; kb < 768; kb += 32) {
    // stage A tile rows [wv*32, wv*32+32)
#pragma unroll
    for (int i = 0; i < 2; i++) {
      int r0 = wv * 32 + i * 16;
      int grow = mT * 128 + r0 + srow;
      int gk = kb + sk;
      size_t off;
      if (MODE == 2) {
        int b = grow / 528, lt = grow - b * 528;
        off = (((size_t)(b * 12 + (gk >> 6)) * 528 + lt) << 6) + (gk & 63);
      } else {
        off = (size_t)grow * 768 + gk;
      }
      __builtin_amdgcn_global_load_lds((gp1_t)(A + off), (lp3_t)(&at[r0 * 32]), 16, 0, 0);
    }
    // stage B tile rows [wv*32, wv*32+32)
#pragma unroll
    for (int i = 0; i < 2; i++) {
      int r0 = wv * 32 + i * 16;
      int grow = nT * 128 + r0 + srow;
      size_t off = (size_t)grow * 768 + kb + sk;
      __builtin_amdgcn_global_load_lds((gp1_t)(Bt + off), (lp3_t)(&bt[r0 * 32]), 16, 0, 0);
    }
    __syncthreads();

    bf16x8 af[4], bf[4];
#pragma unroll
    for (int mi = 0; mi < 4; mi++)
      af[mi] = *(const bf16x8*)&at[(mw + mi * 16 + lane15) * 32 + quad * 8];
#pragma unroll
    for (int ni = 0; ni < 4; ni++)
      bf[ni] = *(const bf16x8*)&bt[(nw + ni * 16 + lane15) * 32 + quad * 8];
#pragma unroll
    for (int mi = 0; mi < 4; mi++)
#pragma unroll
      for (int ni = 0; ni < 4; ni++)
        acc[mi][ni] = MFMA(af[mi], bf[ni], acc[mi][ni]);
    __syncthreads();
  }

  // epilogue: C/D layout col=lane&15, row=quad*4+reg
#pragma unroll
  for (int mi = 0; mi < 4; mi++) {
#pragma unroll
    for (int r = 0; r < 4; r++) {
      int m = mT * 128 + mw + mi * 16 + quad * 4 + r;
#pragma unroll
      for (int ni = 0; ni < 4; ni++) {
        int n = nT * 128 + nw + ni * 16 + lane15;
        float v = acc[mi][ni][r];
        if (MODE == 0) {
          int b = m / 528, lt = m - b * 528;
          ((ushort_t*)C)[(((size_t)(b * 12 + (n >> 6)) * 528 + lt) << 6) + (n & 63)] = f2bf(v);
        } else if (MODE == 1) {
          int b = n / 528, lt = n - b * 528;
          ((ushort_t*)C)[((size_t)(b * 12 + (m >> 6)) * 64 + (m & 63)) * VTP + lt] = f2bf(v);
        } else {
          ((float*)C)[(size_t)m * 768 + n] = v + bias[n];
        }
      }
    }
  }
}

// ---------------- attention: one wave per (bh, 32-row q-tile) ----------------
// tiles 0..3: rows<128 attend 128 keys; tiles 4..15: 528 keys; tile 16: 16 rows, 528 keys.
// No max-subtraction needed: |s*scale| <~ 0.6 so exp() is tame.
__global__ __launch_bounds__(256) void k_attn(ushort_t* __restrict__ Q,
                                              const ushort_t* __restrict__ K,
                                              const ushort_t* __restrict__ Vt) {
  __shared__ ushort_t pbuf[4][32][40];  // per-wave P chunk, 80B rows (16B aligned)
  const int wv = threadIdx.x >> 6, lane = threadIdx.x & 63;
  const int lane15 = lane & 15, quad = lane >> 4;
  const int unit = blockIdx.x * 4 + wv;       // exact: 3264*4 == 768*17
  const int bh = unit / 17, tile = unit - bh * 17;
  const int nk = (tile < 4) ? 128 : 528;
  const int rows0 = tile * 32;
  const int nmt = (tile == 16) ? 1 : 2;

  ushort_t* Qb = Q + (size_t)bh * LQ * DH;
  const ushort_t* Kb = K + (size_t)bh * LQ * DH;
  const ushort_t* Vb = Vt + (size_t)bh * DH * VTP;

  bf16x8 aq[2][2];
#pragma unroll
  for (int mt = 0; mt < 2; mt++) {
    if (mt < nmt) {
#pragma unroll
      for (int ks = 0; ks < 2; ks++)
        aq[mt][ks] = *(const bf16x8*)&Qb[(rows0 + mt * 16 + lane15) * DH + ks * 32 + quad * 8];
    }
  }

  f32x4 o[2][4];
  f32x4 lacc[2];
#pragma unroll
  for (int mt = 0; mt < 2; mt++) {
    lacc[mt] = (f32x4)0.0f;
#pragma unroll
    for (int ni = 0; ni < 4; ni++) o[mt][ni] = (f32x4)0.0f;
  }

  for (int kc = 0; kc < nk; kc += 32) {
    const int kw = (nk - kc) < 32 ? (nk - kc) : 32;  // 32 or 16 (only last of 528)
    const int nnt = kw >> 4;
    bf16x8 kb0[2], kb1[2];
    for (int nt = 0; nt < nnt; nt++) {
      kb0[nt] = *(const bf16x8*)&Kb[(kc + nt * 16 + lane15) * DH + quad * 8];
      kb1[nt] = *(const bf16x8*)&Kb[(kc + nt * 16 + lane15) * DH + 32 + quad * 8];
    }
#pragma unroll
    for (int mt = 0; mt < 2; mt++) {
      if (mt >= nmt) continue;
      for (int nt = 0; nt < nnt; nt++) {
        f32x4 c = (f32x4)0.0f;
        c = MFMA(aq[mt][0], kb0[nt], c);
        c = MFMA(aq[mt][1], kb1[nt], c);
#pragma unroll
        for (int r = 0; r < 4; r++) {
          float p = __expf(c[r] * SCALE);
          lacc[mt][r] += p;
          pbuf[wv][mt * 16 + quad * 4 + r][nt * 16 + lane15] = f2bf(p);
        }
      }
      if (kw == 16) {  // zero-pad P cols 16..31 so the PV MFMA adds 0
#pragma unroll
        for (int r = 0; r < 4; r++) pbuf[wv][mt * 16 + quad * 4 + r][16 + lane15] = 0;
      }
    }
    // PV: A = P (A-layout via LDS), B = V via Vt rows (16B contiguous)
    bf16x8 vb[4];
#pragma unroll
    for (int ni = 0; ni < 4; ni++)
      vb[ni] = *(const bf16x8*)&Vb[(size_t)(ni * 16 + lane15) * VTP + kc + quad * 8];
#pragma unroll
    for (int mt = 0; mt < 2; mt++) {
      if (mt >= nmt) continue;
      bf16x8 pa = *(const bf16x8*)&pbuf[wv][mt * 16 + lane15][quad * 8];
#pragma unroll
      for (int ni = 0; ni < 4; ni++) o[mt][ni] = MFMA(pa, vb[ni], o[mt][ni]);
    }
  }

  // finalize: row sums live distributed over the 16 col-lanes; rows = quad*4+r
#pragma unroll
  for (int mt = 0; mt < 2; mt++) {
    if (mt >= nmt) continue;
#pragma unroll
    for (int r = 0; r < 4; r++) {
      float s = lacc[mt][r];
      s += __shfl_xor(s, 1);
      s += __shfl_xor(s, 2);
      s += __shfl_xor(s, 4);
      s += __shfl_xor(s, 8);
      float inv = 1.0f / s;
#pragma unroll
      for (int ni = 0; ni < 4; ni++)
        Qb[(rows0 + mt * 16 + quad * 4 + r) * DH + ni * 16 + lane15] =
            f2bf(o[mt][ni][r] * inv);
    }
  }
}

// ---------------- launch ----------------
extern "C" void kernel_launch(void* const* d_in, const int* in_sizes, int n_in,
                              void* d_out, int out_size, void* d_ws, size_t ws_size,
                              hipStream_t stream) {
  const float* x = (const float*)d_in[0];
  const float* Wq = (const float*)d_in[1];
  const float* Wk = (const float*)d_in[2];
  const float* Wv = (const float*)d_in[3];
  const float* Wp = (const float*)d_in[4];
  const float* bp = (const float*)d_in[5];
  float* out = (float*)d_out;

  char* ws = (char*)d_ws;
  size_t off = 0;
  auto alloc = [&](size_t bytes) {
    void* p = ws + off;
    off += (bytes + 255) & ~(size_t)255;
    return p;
  };
  ushort_t* xb = (ushort_t*)alloc((size_t)MTOK * DIM * 2);        // 49.5 MiB
  ushort_t* wtq = (ushort_t*)alloc((size_t)DIM * DIM * 2);
  ushort_t* wtk = (ushort_t*)alloc((size_t)DIM * DIM * 2);
  ushort_t* wtv = (ushort_t*)alloc((size_t)DIM * DIM * 2);
  ushort_t* wtp = (ushort_t*)alloc((size_t)DIM * DIM * 2);
  ushort_t* Qb = (ushort_t*)alloc((size_t)MTOK * DIM * 2);        // Q, then attn out in-place
  ushort_t* Kb = (ushort_t*)alloc((size_t)MTOK * DIM * 2);
  ushort_t* Vtb = (ushort_t*)alloc((size_t)BATCH * NH * DH * VTP * 2);
  (void)ws_size; (void)in_sizes; (void)n_in; (void)out_size;

  k_convert_x<<<25344, 256, 0, stream>>>(x, xb);                  // 25952256/4/256
  k_convert_w<<<9216, 256, 0, stream>>>(Wq, Wk, Wv, Wp, wtq, wtk, wtv, wtp);
  k_gemm<0><<<dim3(264, 6), 256, 0, stream>>>(xb, wtq, Qb, nullptr);
  k_gemm<0><<<dim3(264, 6), 256, 0, stream>>>(xb, wtk, Kb, nullptr);
  k_gemm<1><<<dim3(6, 264), 256, 0, stream>>>(wtv, xb, Vtb, nullptr);
  k_attn<<<3264, 256, 0, stream>>>(Qb, Kb, Vtb);
  k_gemm<2><<<dim3(264, 6), 256, 0, stream>>>(Qb, wtp, out, bp);
}

// Round 2
// 591.943 us; speedup vs baseline: 1.8559x; 1.8559x over previous
//
#include <hip/hip_runtime.h>
#include <stdint.h>

typedef __attribute__((ext_vector_type(8))) short bf16x8;
typedef __attribute__((ext_vector_type(4))) float f32x4;
typedef unsigned short ushort_t;
typedef unsigned int u32;
typedef const __attribute__((address_space(1))) u32* gp1_t;
typedef __attribute__((address_space(3))) u32* lp3_t;

#define MFMA(a,b,c) __builtin_amdgcn_mfma_f32_16x16x32_bf16((a),(b),(c),0,0,0)

static constexpr int BATCH = 64, LQ = 528, DIM = 768, NH = 12, DH = 64;
static constexpr int MTOK = BATCH * LQ;   // 33792
static constexpr int VTP  = 544;          // padded Vt row stride (keys)
// scale * log2(e): folded into Q so softmax is a bare exp2
static constexpr float QSCALE = (float)(0.03608439182435161 * 1.4426950408889634);

__device__ __forceinline__ ushort_t f2bf(float f) {
  u32 u = __float_as_uint(f);
  u = (u + 0x7fffu + ((u >> 16) & 1u)) >> 16;
  return (ushort_t)u;
}

// pack hi16(x):hi16(y) -> (x_bf16<<16)|y_bf16 ; inputs pre-rounded (+0x8000)
__device__ __forceinline__ u32 pack2(u32 xr, u32 yr) {
  return __builtin_amdgcn_perm(xr, yr, 0x07060302u);
}

// ---------------- conversion kernels ----------------
__global__ __launch_bounds__(256) void k_convert_x(const float* __restrict__ x,
                                                   ushort_t* __restrict__ xb) {
  int i = blockIdx.x * 256 + threadIdx.x;
  float4 v = ((const float4*)x)[i];
  ushort4 o;
  o.x = f2bf(v.x); o.y = f2bf(v.y); o.z = f2bf(v.z); o.w = f2bf(v.w);
  ((ushort4*)xb)[i] = o;
}

__global__ __launch_bounds__(256) void k_convert_w(
    const float* __restrict__ w0, const float* __restrict__ w1,
    const float* __restrict__ w2, const float* __restrict__ w3,
    ushort_t* __restrict__ o0, ushort_t* __restrict__ o1,
    ushort_t* __restrict__ o2, ushort_t* __restrict__ o3) {
  int i = blockIdx.x * 256 + threadIdx.x;
  int w = i / (DIM * DIM);
  int rem = i - w * (DIM * DIM);
  int k = rem / DIM;
  int n = rem - k * DIM;
  const float* src = (w == 0) ? w0 : (w == 1) ? w1 : (w == 2) ? w2 : w3;
  ushort_t* dst = (w == 0) ? o0 : (w == 1) ? o1 : (w == 2) ? o2 : o3;
  dst[(size_t)n * DIM + k] = f2bf(src[rem]);
}

// ---------------- B^T GEMM, 128x128 tile, BK=32, m97 structure ----------------
template <int MODE>
__global__ __launch_bounds__(256, 2) void k_gemm(const ushort_t* __restrict__ A,
                                                 const ushort_t* __restrict__ Bt,
                                                 void* __restrict__ C,
                                                 const float* __restrict__ bias,
                                                 float scale) {
  __shared__ ushort_t at[128 * 32];
  __shared__ ushort_t bt[128 * 32];
  const int tid = threadIdx.x;
  const int wv = tid >> 6, lane = tid & 63;
  const int lane15 = lane & 15, quad = lane >> 4;
  const int mT = blockIdx.x, nT = blockIdx.y;
  const int mw = (wv & 1) * 64, nw = (wv >> 1) * 64;

  f32x4 acc[4][4];
#pragma unroll
  for (int i = 0; i < 4; i++)
#pragma unroll
    for (int j = 0; j < 4; j++) acc[i][j] = (f32x4)0.0f;

  const int srow = lane >> 2;
  const int sk = (lane & 3) * 8;

  for (int kb = 0; kb < 768; kb += 32) {
#pragma unroll
    for (int i = 0; i < 2; i++) {
      int r0 = wv * 32 + i * 16;
      int grow = mT * 128 + r0 + srow;
      int gk = kb + sk;
      size_t off;
      if (MODE == 2) {
        int b = grow / 528, lt = grow - b * 528;
        off = (((size_t)(b * 12 + (gk >> 6)) * 528 + lt) << 6) + (gk & 63);
      } else {
        off = (size_t)grow * 768 + gk;
      }
      __builtin_amdgcn_global_load_lds((gp1_t)(A + off), (lp3_t)(&at[r0 * 32]), 16, 0, 0);
    }
#pragma unroll
    for (int i = 0; i < 2; i++) {
      int r0 = wv * 32 + i * 16;
      int grow = nT * 128 + r0 + srow;
      size_t off = (size_t)grow * 768 + kb + sk;
      __builtin_amdgcn_global_load_lds((gp1_t)(Bt + off), (lp3_t)(&bt[r0 * 32]), 16, 0, 0);
    }
    __syncthreads();

    bf16x8 af[4], bf[4];
#pragma unroll
    for (int mi = 0; mi < 4; mi++)
      af[mi] = *(const bf16x8*)&at[(mw + mi * 16 + lane15) * 32 + quad * 8];
#pragma unroll
    for (int ni = 0; ni < 4; ni++)
      bf[ni] = *(const bf16x8*)&bt[(nw + ni * 16 + lane15) * 32 + quad * 8];
#pragma unroll
    for (int mi = 0; mi < 4; mi++)
#pragma unroll
      for (int ni = 0; ni < 4; ni++)
        acc[mi][ni] = MFMA(af[mi], bf[ni], acc[mi][ni]);
    __syncthreads();
  }

#pragma unroll
  for (int mi = 0; mi < 4; mi++) {
#pragma unroll
    for (int r = 0; r < 4; r++) {
      int m = mT * 128 + mw + mi * 16 + quad * 4 + r;
#pragma unroll
      for (int ni = 0; ni < 4; ni++) {
        int n = nT * 128 + nw + ni * 16 + lane15;
        float v = acc[mi][ni][r];
        if (MODE == 0) {
          int b = m / 528, lt = m - b * 528;
          ((ushort_t*)C)[(((size_t)(b * 12 + (n >> 6)) * 528 + lt) << 6) + (n & 63)] =
              f2bf(v * scale);
        } else if (MODE == 1) {
          int b = n / 528, lt = n - b * 528;
          ((ushort_t*)C)[((size_t)(b * 12 + (m >> 6)) * 64 + (m & 63)) * VTP + lt] = f2bf(v);
        } else {
          ((float*)C)[(size_t)m * 768 + n] = v + bias[n];
        }
      }
    }
  }
}

// ---------------- attention v2: S^T trick, no LDS, no shuffles ----------------
// Wave = (bh, 32 q-rows). S^T = K·Q^T with permuted K rows so two exp'd C-frags
// concatenate in-register into the 16x16x32 B-operand for O^T = V^T·P^T.
// Row sums via one extra MFMA with A=ones. Output stored in-place over Q.
__global__ __launch_bounds__(256) void k_attn(ushort_t* __restrict__ Q,
                                              const ushort_t* __restrict__ K,
                                              const ushort_t* __restrict__ Vt) {
  const int wv = threadIdx.x >> 6, lane = threadIdx.x & 63;
  const int lane15 = lane & 15, quad = lane >> 4;
  const int unit = blockIdx.x * 4 + wv;       // 3264*4 == 768*17
  const int bh = unit / 17, tile = unit - bh * 17;
  const int nk = (tile < 4) ? 128 : 528;
  const int rows0 = tile * 32;
  const int nmt = (tile == 16) ? 1 : 2;

  ushort_t* Qb = Q + (size_t)bh * LQ * DH;
  const ushort_t* Kb = K + (size_t)bh * LQ * DH;
  const ushort_t* Vb = Vt + (size_t)bh * DH * VTP;

  // Q frags (B-operand: lane15 = qrow, quad*8+j = d) — Q pre-scaled by QSCALE
  bf16x8 aq[2][2];
#pragma unroll
  for (int mt = 0; mt < 2; mt++)
#pragma unroll
    for (int h = 0; h < 2; h++)
      aq[mt][h] = *(const bf16x8*)&Qb[(size_t)(rows0 + mt * 16 + lane15) * DH + h * 32 + quad * 8];

  f32x4 o[2][4], sm[2];
#pragma unroll
  for (int mt = 0; mt < 2; mt++) {
    sm[mt] = (f32x4)0.0f;
#pragma unroll
    for (int dt = 0; dt < 4; dt++) o[mt][dt] = (f32x4)0.0f;
  }

  bf16x8 ones;
#pragma unroll
  for (int i = 0; i < 8; i++) ones[i] = (short)0x3F80;  // bf16 1.0

  // permuted K-row base: set s covers keys quad*8 + s*4 + r after C-layout
  const int krp = ((lane15 >> 2) << 3) + (lane15 & 3);

  for (int kc = 0; kc < nk; kc += 32) {
    const bool tail = (kc + 32 > nk);  // only kc=512 (16 keys)
    bf16x8 kf[2][2], vf[4];
#pragma unroll
    for (int s = 0; s < 2; s++) {
      size_t kr = (size_t)(kc + krp + s * 4) * DH;
      kf[s][0] = *(const bf16x8*)&Kb[kr + quad * 8];
      kf[s][1] = *(const bf16x8*)&Kb[kr + 32 + quad * 8];
    }
#pragma unroll
    for (int dt = 0; dt < 4; dt++)
      vf[dt] = *(const bf16x8*)&Vb[(size_t)(dt * 16 + lane15) * VTP + kc + quad * 8];

#pragma unroll
    for (int mt = 0; mt < 2; mt++) {
      f32x4 c0 = (f32x4)0.0f, c1 = (f32x4)0.0f;
      c0 = MFMA(kf[0][0], aq[mt][0], c0);
      c0 = MFMA(kf[0][1], aq[mt][1], c0);
      c1 = MFMA(kf[1][0], aq[mt][0], c1);
      c1 = MFMA(kf[1][1], aq[mt][1], c1);
      u32 pw[8];
#pragma unroll
      for (int r = 0; r < 4; r++) {
        float e0 = exp2f(c0[r]);
        float e1 = exp2f(c1[r]);
        if (tail) {  // wave-uniform branch; zero keys >= nk (quads 2,3)
          float zm = (quad < 2) ? 1.0f : 0.0f;
          e0 *= zm; e1 *= zm;
        }
        pw[r]     = __float_as_uint(e0) + 0x8000u;
        pw[4 + r] = __float_as_uint(e1) + 0x8000u;
      }
      union { bf16x8 v; u32 w[4]; } pb;
      pb.w[0] = pack2(pw[1], pw[0]);
      pb.w[1] = pack2(pw[3], pw[2]);
      pb.w[2] = pack2(pw[5], pw[4]);
      pb.w[3] = pack2(pw[7], pw[6]);
      sm[mt] = MFMA(ones, pb.v, sm[mt]);
#pragma unroll
      for (int dt = 0; dt < 4; dt++)
        o[mt][dt] = MFMA(vf[dt], pb.v, o[mt][dt]);
    }
  }

  // epilogue: O^T C-layout row = d = quad*4+r (consecutive!), col = qrow = lane15
#pragma unroll
  for (int mt = 0; mt < 2; mt++) {
    if (mt >= nmt) continue;
    float inv = 1.0f / sm[mt][0];  // all regs/rows replicated
    ushort_t* orow = &Qb[(size_t)(rows0 + mt * 16 + lane15) * DH];
#pragma unroll
    for (int dt = 0; dt < 4; dt++) {
      u32 r0 = __float_as_uint(o[mt][dt][0] * inv) + 0x8000u;
      u32 r1 = __float_as_uint(o[mt][dt][1] * inv) + 0x8000u;
      u32 r2 = __float_as_uint(o[mt][dt][2] * inv) + 0x8000u;
      u32 r3 = __float_as_uint(o[mt][dt][3] * inv) + 0x8000u;
      uint2 st;
      st.x = pack2(r1, r0);
      st.y = pack2(r3, r2);
      *(uint2*)&orow[dt * 16 + quad * 4] = st;
    }
  }
}

// ---------------- launch ----------------
extern "C" void kernel_launch(void* const* d_in, const int* in_sizes, int n_in,
                              void* d_out, int out_size, void* d_ws, size_t ws_size,
                              hipStream_t stream) {
  const float* x = (const float*)d_in[0];
  const float* Wq = (const float*)d_in[1];
  const float* Wk = (const float*)d_in[2];
  const float* Wv = (const float*)d_in[3];
  const float* Wp = (const float*)d_in[4];
  const float* bp = (const float*)d_in[5];
  float* out = (float*)d_out;

  char* ws = (char*)d_ws;
  size_t off = 0;
  auto alloc = [&](size_t bytes) {
    void* p = ws + off;
    off += (bytes + 255) & ~(size_t)255;
    return p;
  };
  ushort_t* xb = (ushort_t*)alloc((size_t)MTOK * DIM * 2);
  ushort_t* wtq = (ushort_t*)alloc((size_t)DIM * DIM * 2);
  ushort_t* wtk = (ushort_t*)alloc((size_t)DIM * DIM * 2);
  ushort_t* wtv = (ushort_t*)alloc((size_t)DIM * DIM * 2);
  ushort_t* wtp = (ushort_t*)alloc((size_t)DIM * DIM * 2);
  ushort_t* Qb = (ushort_t*)alloc((size_t)MTOK * DIM * 2);   // Q, then attn out in-place
  ushort_t* Kb = (ushort_t*)alloc((size_t)MTOK * DIM * 2);
  ushort_t* Vtb = (ushort_t*)alloc((size_t)BATCH * NH * DH * VTP * 2);
  (void)ws_size; (void)in_sizes; (void)n_in; (void)out_size;

  k_convert_x<<<25344, 256, 0, stream>>>(x, xb);
  k_convert_w<<<9216, 256, 0, stream>>>(Wq, Wk, Wv, Wp, wtq, wtk, wtv, wtp);
  k_gemm<0><<<dim3(264, 6), 256, 0, stream>>>(xb, wtq, Qb, nullptr, QSCALE);
  k_gemm<0><<<dim3(264, 6), 256, 0, stream>>>(xb, wtk, Kb, nullptr, 1.0f);
  k_gemm<1><<<dim3(6, 264), 256, 0, stream>>>(wtv, xb, Vtb, nullptr, 1.0f);
  k_attn<<<3264, 256, 0, stream>>>(Qb, Kb, Vtb);
  k_gemm<2><<<dim3(264, 6), 256, 0, stream>>>(Qb, wtp, out, bp, 1.0f);
}

// Round 3
// 589.528 us; speedup vs baseline: 1.8635x; 1.0041x over previous
//
#include <hip/hip_runtime.h>
#include <stdint.h>

typedef __attribute__((ext_vector_type(8))) short bf16x8;
typedef __attribute__((ext_vector_type(4))) float f32x4;
typedef unsigned short ushort_t;
typedef unsigned int u32;
typedef const __attribute__((address_space(1))) u32* gp1_t;
typedef __attribute__((address_space(3))) u32* lp3_t;

#define MFMA(a,b,c) __builtin_amdgcn_mfma_f32_16x16x32_bf16((a),(b),(c),0,0,0)

static constexpr int BATCH = 64, LQ = 528, DIM = 768, NH = 12, DH = 64;
static constexpr int MTOK = BATCH * LQ;   // 33792
static constexpr int VTP  = 544;          // padded Vt row stride (keys)
// scale * log2(e): folded into Q so softmax is a bare exp2
static constexpr float QSCALE = (float)(0.03608439182435161 * 1.4426950408889634);

__device__ __forceinline__ ushort_t f2bf(float f) {
  u32 u = __float_as_uint(f);
  u = (u + 0x7fffu + ((u >> 16) & 1u)) >> 16;
  return (ushort_t)u;
}

// pack hi16(x):hi16(y) -> (x_bf16<<16)|y_bf16 ; inputs pre-rounded (+0x8000)
__device__ __forceinline__ u32 pack2(u32 xr, u32 yr) {
  return __builtin_amdgcn_perm(xr, yr, 0x07060302u);
}

// ---------------- conversion kernels ----------------
__global__ __launch_bounds__(256) void k_convert_x(const float* __restrict__ x,
                                                   ushort_t* __restrict__ xb) {
  int i = blockIdx.x * 256 + threadIdx.x;
  float4 v = ((const float4*)x)[i];
  ushort4 o;
  o.x = f2bf(v.x); o.y = f2bf(v.y); o.z = f2bf(v.z); o.w = f2bf(v.w);
  ((ushort4*)xb)[i] = o;
}

__global__ __launch_bounds__(256) void k_convert_w(
    const float* __restrict__ w0, const float* __restrict__ w1,
    const float* __restrict__ w2, const float* __restrict__ w3,
    ushort_t* __restrict__ o0, ushort_t* __restrict__ o1,
    ushort_t* __restrict__ o2, ushort_t* __restrict__ o3) {
  int i = blockIdx.x * 256 + threadIdx.x;
  int w = i / (DIM * DIM);
  int rem = i - w * (DIM * DIM);
  int k = rem / DIM;
  int n = rem - k * DIM;
  const float* src = (w == 0) ? w0 : (w == 1) ? w1 : (w == 2) ? w2 : w3;
  ushort_t* dst = (w == 0) ? o0 : (w == 1) ? o1 : (w == 2) ? o2 : o3;
  dst[(size_t)n * DIM + k] = f2bf(src[rem]);
}

// ---------------- B^T GEMM, 128x128 tile, BK=32, m97 structure ----------------
template <int MODE>
__global__ __launch_bounds__(256, 2) void k_gemm(const ushort_t* __restrict__ A,
                                                 const ushort_t* __restrict__ Bt,
                                                 void* __restrict__ C,
                                                 const float* __restrict__ bias,
                                                 float scale) {
  __shared__ ushort_t at[128 * 32];
  __shared__ ushort_t bt[128 * 32];
  const int tid = threadIdx.x;
  const int wv = tid >> 6, lane = tid & 63;
  const int lane15 = lane & 15, quad = lane >> 4;
  const int mT = blockIdx.x, nT = blockIdx.y;
  const int mw = (wv & 1) * 64, nw = (wv >> 1) * 64;

  f32x4 acc[4][4];
#pragma unroll
  for (int i = 0; i < 4; i++)
#pragma unroll
    for (int j = 0; j < 4; j++) acc[i][j] = (f32x4)0.0f;

  const int srow = lane >> 2;
  const int sk = (lane & 3) * 8;

  for (int kb = 0; kb < 768; kb += 32) {
#pragma unroll
    for (int i = 0; i < 2; i++) {
      int r0 = wv * 32 + i * 16;
      int grow = mT * 128 + r0 + srow;
      int gk = kb + sk;
      size_t off;
      if (MODE == 2) {
        int b = grow / 528, lt = grow - b * 528;
        off = (((size_t)(b * 12 + (gk >> 6)) * 528 + lt) << 6) + (gk & 63);
      } else {
        off = (size_t)grow * 768 + gk;
      }
      __builtin_amdgcn_global_load_lds((gp1_t)(A + off), (lp3_t)(&at[r0 * 32]), 16, 0, 0);
    }
#pragma unroll
    for (int i = 0; i < 2; i++) {
      int r0 = wv * 32 + i * 16;
      int grow = nT * 128 + r0 + srow;
      size_t off = (size_t)grow * 768 + kb + sk;
      __builtin_amdgcn_global_load_lds((gp1_t)(Bt + off), (lp3_t)(&bt[r0 * 32]), 16, 0, 0);
    }
    __syncthreads();

    bf16x8 af[4], bf[4];
#pragma unroll
    for (int mi = 0; mi < 4; mi++)
      af[mi] = *(const bf16x8*)&at[(mw + mi * 16 + lane15) * 32 + quad * 8];
#pragma unroll
    for (int ni = 0; ni < 4; ni++)
      bf[ni] = *(const bf16x8*)&bt[(nw + ni * 16 + lane15) * 32 + quad * 8];
#pragma unroll
    for (int mi = 0; mi < 4; mi++)
#pragma unroll
      for (int ni = 0; ni < 4; ni++)
        acc[mi][ni] = MFMA(af[mi], bf[ni], acc[mi][ni]);
    __syncthreads();
  }

#pragma unroll
  for (int mi = 0; mi < 4; mi++) {
#pragma unroll
    for (int r = 0; r < 4; r++) {
      int m = mT * 128 + mw + mi * 16 + quad * 4 + r;
#pragma unroll
      for (int ni = 0; ni < 4; ni++) {
        int n = nT * 128 + nw + ni * 16 + lane15;
        float v = acc[mi][ni][r];
        if (MODE == 0) {
          int b = m / 528, lt = m - b * 528;
          ((ushort_t*)C)[(((size_t)(b * 12 + (n >> 6)) * 528 + lt) << 6) + (n & 63)] =
              f2bf(v * scale);
        } else if (MODE == 1) {
          int b = n / 528, lt = n - b * 528;
          ((ushort_t*)C)[((size_t)(b * 12 + (m >> 6)) * 64 + (m & 63)) * VTP + lt] = f2bf(v);
        } else {
          ((float*)C)[(size_t)m * 768 + n] = v + bias[n];
        }
      }
    }
  }
}

// ---------------- attention v3: S^T trick + prefetch pipeline + XCD swizzle ----
__global__ __launch_bounds__(256, 3) void k_attn(ushort_t* __restrict__ Q,
                                                 const ushort_t* __restrict__ K,
                                                 const ushort_t* __restrict__ Vt) {
  const int wv = threadIdx.x >> 6, lane = threadIdx.x & 63;
  const int lane15 = lane & 15, quad = lane >> 4;
  // XCD swizzle: phys block b -> logical (b&7)*408 + (b>>3). Each XCD gets a
  // contiguous bh range (96 bh x 17 units) -> K/V L2 reuse, balanced load.
  const int b = blockIdx.x;
  const int logical = (b & 7) * 408 + (b >> 3);
  const int unit = logical * 4 + wv;          // 3264*4 == 768*17
  const int bh = unit / 17, tile = unit - bh * 17;
  const int nch = (tile < 4) ? 4 : 17;        // 32-key chunks (chunk 16 = tail)
  const int rows0 = tile * 32;
  const int nmt = (tile == 16) ? 1 : 2;

  ushort_t* Qb = Q + (size_t)bh * LQ * DH;
  const ushort_t* Kb = K + (size_t)bh * LQ * DH;
  const ushort_t* Vb = Vt + (size_t)bh * DH * VTP;

  // Q frags (B-operand: lane15 = qrow, quad*8+j = d) — Q pre-scaled by QSCALE
  bf16x8 aq[2][2];
#pragma unroll
  for (int mt = 0; mt < 2; mt++)
#pragma unroll
    for (int h = 0; h < 2; h++)
      aq[mt][h] = *(const bf16x8*)&Qb[(size_t)(rows0 + mt * 16 + lane15) * DH + h * 32 + quad * 8];

  f32x4 o[2][4], sm[2];
#pragma unroll
  for (int mt = 0; mt < 2; mt++) {
    sm[mt] = (f32x4)0.0f;
#pragma unroll
    for (int dt = 0; dt < 4; dt++) o[mt][dt] = (f32x4)0.0f;
  }

  bf16x8 ones;
#pragma unroll
  for (int i = 0; i < 8; i++) ones[i] = (short)0x3F80;  // bf16 1.0

  // permuted K-row base: after S^T C-layout, key = kc + quad*8 + s*4 + r
  const int krp = ((lane15 >> 2) << 3) + (lane15 & 3);
  const ushort_t* kbase = Kb + (size_t)krp * DH + quad * 8;
  const ushort_t* vbase = Vb + (size_t)lane15 * VTP + quad * 8;

  auto loadK = [&](int kc, bf16x8 kf[2][2]) {
#pragma unroll
    for (int s = 0; s < 2; s++) {
      const ushort_t* p = kbase + (size_t)(kc + s * 4) * DH;
      kf[s][0] = *(const bf16x8*)&p[0];
      kf[s][1] = *(const bf16x8*)&p[32];
    }
  };
  auto loadV = [&](int kc, bf16x8 vf[4]) {
#pragma unroll
    for (int dt = 0; dt < 4; dt++)
      vf[dt] = *(const bf16x8*)&vbase[(size_t)dt * 16 * VTP + kc];
  };
  auto compute = [&](bf16x8 kf[2][2], bf16x8 vf[4], bool tailmask) {
#pragma unroll
    for (int mt = 0; mt < 2; mt++) {
      if (mt == 1 && nmt == 1) continue;  // tile 16: only 16 valid rows
      f32x4 c0 = (f32x4)0.0f, c1 = (f32x4)0.0f;
      c0 = MFMA(kf[0][0], aq[mt][0], c0);
      c0 = MFMA(kf[0][1], aq[mt][1], c0);
      c1 = MFMA(kf[1][0], aq[mt][0], c1);
      c1 = MFMA(kf[1][1], aq[mt][1], c1);
      u32 pw[8];
#pragma unroll
      for (int r = 0; r < 4; r++) {
        float e0 = exp2f(c0[r]);
        float e1 = exp2f(c1[r]);
        if (tailmask) {  // zero keys >= 528 (quads 2,3 of chunk 16)
          float zm = (quad < 2) ? 1.0f : 0.0f;
          e0 *= zm; e1 *= zm;
        }
        pw[r]     = __float_as_uint(e0) + 0x8000u;
        pw[4 + r] = __float_as_uint(e1) + 0x8000u;
      }
      union { bf16x8 v; u32 w[4]; } pb;
      pb.w[0] = pack2(pw[1], pw[0]);
      pb.w[1] = pack2(pw[3], pw[2]);
      pb.w[2] = pack2(pw[5], pw[4]);
      pb.w[3] = pack2(pw[7], pw[6]);
      sm[mt] = MFMA(ones, pb.v, sm[mt]);
#pragma unroll
      for (int dt = 0; dt < 4; dt++)
        o[mt][dt] = MFMA(vf[dt], pb.v, o[mt][dt]);
    }
  };

  // software pipeline: prefetch next chunk while computing current (no reg copies)
  bf16x8 kfA[2][2], vfA[4], kfB[2][2], vfB[4];
  loadK(0, kfA);
  loadV(0, vfA);
  int c = 0;
  for (; c + 1 < nch; c += 2) {
    loadK((c + 1) * 32, kfB);
    loadV((c + 1) * 32, vfB);
    compute(kfA, vfA, false);
    if (c + 2 < nch) {
      loadK((c + 2) * 32, kfA);
      loadV((c + 2) * 32, vfA);
    }
    compute(kfB, vfB, false);
  }
  if (c < nch) compute(kfA, vfA, true);  // heavy tail: chunk 16, 16 valid keys

  // epilogue: O^T C-layout row = d = quad*4+r (consecutive), col = qrow = lane15
#pragma unroll
  for (int mt = 0; mt < 2; mt++) {
    if (mt >= nmt) continue;
    float inv = 1.0f / sm[mt][0];  // replicated across regs
    ushort_t* orow = &Qb[(size_t)(rows0 + mt * 16 + lane15) * DH];
#pragma unroll
    for (int dt = 0; dt < 4; dt++) {
      u32 r0 = __float_as_uint(o[mt][dt][0] * inv) + 0x8000u;
      u32 r1 = __float_as_uint(o[mt][dt][1] * inv) + 0x8000u;
      u32 r2 = __float_as_uint(o[mt][dt][2] * inv) + 0x8000u;
      u32 r3 = __float_as_uint(o[mt][dt][3] * inv) + 0x8000u;
      uint2 st;
      st.x = pack2(r1, r0);
      st.y = pack2(r3, r2);
      *(uint2*)&orow[dt * 16 + quad * 4] = st;
    }
  }
}

// ---------------- launch ----------------
extern "C" void kernel_launch(void* const* d_in, const int* in_sizes, int n_in,
                              void* d_out, int out_size, void* d_ws, size_t ws_size,
                              hipStream_t stream) {
  const float* x = (const float*)d_in[0];
  const float* Wq = (const float*)d_in[1];
  const float* Wk = (const float*)d_in[2];
  const float* Wv = (const float*)d_in[3];
  const float* Wp = (const float*)d_in[4];
  const float* bp = (const float*)d_in[5];
  float* out = (float*)d_out;

  char* ws = (char*)d_ws;
  size_t off = 0;
  auto alloc = [&](size_t bytes) {
    void* p = ws + off;
    off += (bytes + 255) & ~(size_t)255;
    return p;
  };
  ushort_t* xb = (ushort_t*)alloc((size_t)MTOK * DIM * 2);
  ushort_t* wtq = (ushort_t*)alloc((size_t)DIM * DIM * 2);
  ushort_t* wtk = (ushort_t*)alloc((size_t)DIM * DIM * 2);
  ushort_t* wtv = (ushort_t*)alloc((size_t)DIM * DIM * 2);
  ushort_t* wtp = (ushort_t*)alloc((size_t)DIM * DIM * 2);
  ushort_t* Qb = (ushort_t*)alloc((size_t)MTOK * DIM * 2);   // Q, then attn out in-place
  ushort_t* Kb = (ushort_t*)alloc((size_t)MTOK * DIM * 2);
  ushort_t* Vtb = (ushort_t*)alloc((size_t)BATCH * NH * DH * VTP * 2);
  (void)ws_size; (void)in_sizes; (void)n_in; (void)out_size;

  k_convert_x<<<25344, 256, 0, stream>>>(x, xb);
  k_convert_w<<<9216, 256, 0, stream>>>(Wq, Wk, Wv, Wp, wtq, wtk, wtv, wtp);
  k_gemm<0><<<dim3(264, 6), 256, 0, stream>>>(xb, wtq, Qb, nullptr, QSCALE);
  k_gemm<0><<<dim3(264, 6), 256, 0, stream>>>(xb, wtk, Kb, nullptr, 1.0f);
  k_gemm<1><<<dim3(6, 264), 256, 0, stream>>>(wtv, xb, Vtb, nullptr, 1.0f);
  k_attn<<<3264, 256, 0, stream>>>(Qb, Kb, Vtb);
  k_gemm<2><<<dim3(264, 6), 256, 0, stream>>>(Qb, wtp, out, bp, 1.0f);
}

// Round 4
// 524.110 us; speedup vs baseline: 2.0961x; 1.1248x over previous
//
#include <hip/hip_runtime.h>
#include <stdint.h>

typedef __attribute__((ext_vector_type(8))) short bf16x8;
typedef __attribute__((ext_vector_type(4))) float f32x4;
typedef unsigned short ushort_t;
typedef unsigned int u32;
typedef const __attribute__((address_space(1))) u32* gp1_t;
typedef __attribute__((address_space(3))) u32* lp3_t;

#define MFMA(a,b,c) __builtin_amdgcn_mfma_f32_16x16x32_bf16((a),(b),(c),0,0,0)

static constexpr int BATCH = 64, LQ = 528, DIM = 768, NH = 12, DH = 64;
static constexpr int MTOK = BATCH * LQ;   // 33792
static constexpr int VTP  = 544;          // padded Vt row stride (keys)
// scale * log2(e): folded into Q so softmax is a bare exp2
static constexpr float QSCALE = (float)(0.03608439182435161 * 1.4426950408889634);

__device__ __forceinline__ ushort_t f2bf(float f) {
  u32 u = __float_as_uint(f);
  u = (u + 0x7fffu + ((u >> 16) & 1u)) >> 16;
  return (ushort_t)u;
}
__device__ __forceinline__ u32 pack2(u32 xr, u32 yr) {  // lo=yr.bf16, hi=xr.bf16
  return __builtin_amdgcn_perm(xr, yr, 0x07060302u);
}
__device__ __forceinline__ int swzK(int r) { return (r & 3) | (((r >> 3) & 1) << 2); }
__device__ __forceinline__ int swzV(int d) { return (d >> 2) & 3; }

// ---------------- conversion kernels ----------------
__global__ __launch_bounds__(256) void k_convert_x(const float* __restrict__ x,
                                                   ushort_t* __restrict__ xb) {
  int i = blockIdx.x * 256 + threadIdx.x;
  float4 v = ((const float4*)x)[i];
  ushort4 o;
  o.x = f2bf(v.x); o.y = f2bf(v.y); o.z = f2bf(v.z); o.w = f2bf(v.w);
  ((ushort4*)xb)[i] = o;
}

// LDS-tiled transpose: W[k][n] f32 -> Wt[n][k] bf16, coalesced both sides
__global__ __launch_bounds__(256) void k_convert_w(
    const float* __restrict__ w0, const float* __restrict__ w1,
    const float* __restrict__ w2, const float* __restrict__ w3,
    ushort_t* __restrict__ o0, ushort_t* __restrict__ o1,
    ushort_t* __restrict__ o2, ushort_t* __restrict__ o3) {
  __shared__ ushort_t t[64][65];
  int mid = blockIdx.z;
  const float* src = (mid == 0) ? w0 : (mid == 1) ? w1 : (mid == 2) ? w2 : w3;
  ushort_t* dst = (mid == 0) ? o0 : (mid == 1) ? o1 : (mid == 2) ? o2 : o3;
  int k0 = blockIdx.x * 64, n0 = blockIdx.y * 64;
  int c = threadIdx.x & 63, rr = threadIdx.x >> 6;
#pragma unroll
  for (int p = 0; p < 16; p++) {
    int r = p * 4 + rr;
    t[c][r] = f2bf(src[(size_t)(k0 + r) * DIM + n0 + c]);
  }
  __syncthreads();
#pragma unroll
  for (int p = 0; p < 16; p++) {
    int r = p * 4 + rr;
    dst[(size_t)(n0 + r) * DIM + k0 + c] = t[r][c];
  }
}

// ---------------- fused QKV GEMM, 128x128 tile, BK=32 ----------------
// C[m][n] = sum_k xb[m][k] * Wt[n][k]; w=0->Q(scaled), 1->K, 2->V(transposed dest)
__global__ __launch_bounds__(256, 2) void k_gemm_qkv(
    const ushort_t* __restrict__ A, const ushort_t* __restrict__ wq,
    const ushort_t* __restrict__ wk, const ushort_t* __restrict__ wv,
    ushort_t* __restrict__ Qb, ushort_t* __restrict__ Kb, ushort_t* __restrict__ Vtb) {
  // XCD swizzle: 4752 = 8 * (33 mT * 18 nt); same-mT blocks consecutive per XCD
  const int id = blockIdx.x, xcd = id & 7, s = id >> 3;
  const int mT = xcd * 33 + s / 18, t = s % 18, w = t / 6, nT = t % 6;
  const ushort_t* Bt = (w == 0) ? wq : (w == 1) ? wk : wv;

  __shared__ ushort_t at[128 * 32];
  __shared__ ushort_t bt[128 * 32];
  const int tid = threadIdx.x;
  const int wv_ = tid >> 6, lane = tid & 63;
  const int lane15 = lane & 15, quad = lane >> 4;
  const int mw = (wv_ & 1) * 64, nw = (wv_ >> 1) * 64;

  f32x4 acc[4][4];
#pragma unroll
  for (int i = 0; i < 4; i++)
#pragma unroll
    for (int j = 0; j < 4; j++) acc[i][j] = (f32x4)0.0f;

  const int srow = lane >> 2;
  const int sk = (lane & 3) * 8;

  for (int kb = 0; kb < 768; kb += 32) {
#pragma unroll
    for (int i = 0; i < 2; i++) {
      int r0 = wv_ * 32 + i * 16;
      size_t off = (size_t)(mT * 128 + r0 + srow) * 768 + kb + sk;
      __builtin_amdgcn_global_load_lds((gp1_t)(A + off), (lp3_t)(&at[r0 * 32]), 16, 0, 0);
    }
#pragma unroll
    for (int i = 0; i < 2; i++) {
      int r0 = wv_ * 32 + i * 16;
      size_t off = (size_t)(nT * 128 + r0 + srow) * 768 + kb + sk;
      __builtin_amdgcn_global_load_lds((gp1_t)(Bt + off), (lp3_t)(&bt[r0 * 32]), 16, 0, 0);
    }
    __syncthreads();
    bf16x8 af[4], bf[4];
#pragma unroll
    for (int mi = 0; mi < 4; mi++)
      af[mi] = *(const bf16x8*)&at[(mw + mi * 16 + lane15) * 32 + quad * 8];
#pragma unroll
    for (int ni = 0; ni < 4; ni++)
      bf[ni] = *(const bf16x8*)&bt[(nw + ni * 16 + lane15) * 32 + quad * 8];
#pragma unroll
    for (int mi = 0; mi < 4; mi++)
#pragma unroll
      for (int ni = 0; ni < 4; ni++)
        acc[mi][ni] = MFMA(af[mi], bf[ni], acc[mi][ni]);
    __syncthreads();
  }

  const float scale = (w == 0) ? QSCALE : 1.0f;
  ushort_t* Cqk = (w == 0) ? Qb : Kb;
#pragma unroll
  for (int mi = 0; mi < 4; mi++) {
#pragma unroll
    for (int r = 0; r < 4; r++) {
      int m = mT * 128 + mw + mi * 16 + quad * 4 + r;
      int b = m / 528, lt = m - b * 528;
#pragma unroll
      for (int ni = 0; ni < 4; ni++) {
        int n = nT * 128 + nw + ni * 16 + lane15;
        float v = acc[mi][ni][r];
        if (w < 2) {
          Cqk[(((size_t)(b * 12 + (n >> 6)) * 528 + lt) << 6) + (n & 63)] = f2bf(v * scale);
        } else {
          Vtb[((size_t)(b * 12 + (n >> 6)) * 64 + (n & 63)) * VTP + lt] = f2bf(v);
        }
      }
    }
  }
}

// ---------------- out-proj GEMM (reads attn out in (b,h,l,d), writes fp32+bias) --
__global__ __launch_bounds__(256, 2) void k_gemm_out(const ushort_t* __restrict__ A,
                                                     const ushort_t* __restrict__ Bt,
                                                     float* __restrict__ C,
                                                     const float* __restrict__ bias) {
  const int id = blockIdx.x, xcd = id & 7, s = id >> 3;  // 1584 = 8*(33*6)
  const int mT = xcd * 33 + s / 6, nT = s % 6;

  __shared__ ushort_t at[128 * 32];
  __shared__ ushort_t bt[128 * 32];
  const int tid = threadIdx.x;
  const int wv_ = tid >> 6, lane = tid & 63;
  const int lane15 = lane & 15, quad = lane >> 4;
  const int mw = (wv_ & 1) * 64, nw = (wv_ >> 1) * 64;

  f32x4 acc[4][4];
#pragma unroll
  for (int i = 0; i < 4; i++)
#pragma unroll
    for (int j = 0; j < 4; j++) acc[i][j] = (f32x4)0.0f;

  const int srow = lane >> 2;
  const int sk = (lane & 3) * 8;

  for (int kb = 0; kb < 768; kb += 32) {
#pragma unroll
    for (int i = 0; i < 2; i++) {
      int r0 = wv_ * 32 + i * 16;
      int grow = mT * 128 + r0 + srow;
      int gk = kb + sk;
      int b = grow / 528, lt = grow - b * 528;
      size_t off = (((size_t)(b * 12 + (gk >> 6)) * 528 + lt) << 6) + (gk & 63);
      __builtin_amdgcn_global_load_lds((gp1_t)(A + off), (lp3_t)(&at[r0 * 32]), 16, 0, 0);
    }
#pragma unroll
    for (int i = 0; i < 2; i++) {
      int r0 = wv_ * 32 + i * 16;
      size_t off = (size_t)(nT * 128 + r0 + srow) * 768 + kb + sk;
      __builtin_amdgcn_global_load_lds((gp1_t)(Bt + off), (lp3_t)(&bt[r0 * 32]), 16, 0, 0);
    }
    __syncthreads();
    bf16x8 af[4], bf[4];
#pragma unroll
    for (int mi = 0; mi < 4; mi++)
      af[mi] = *(const bf16x8*)&at[(mw + mi * 16 + lane15) * 32 + quad * 8];
#pragma unroll
    for (int ni = 0; ni < 4; ni++)
      bf[ni] = *(const bf16x8*)&bt[(nw + ni * 16 + lane15) * 32 + quad * 8];
#pragma unroll
    for (int mi = 0; mi < 4; mi++)
#pragma unroll
      for (int ni = 0; ni < 4; ni++)
        acc[mi][ni] = MFMA(af[mi], bf[ni], acc[mi][ni]);
    __syncthreads();
  }

#pragma unroll
  for (int mi = 0; mi < 4; mi++) {
#pragma unroll
    for (int r = 0; r < 4; r++) {
      int m = mT * 128 + mw + mi * 16 + quad * 4 + r;
#pragma unroll
      for (int ni = 0; ni < 4; ni++) {
        int n = nT * 128 + nw + ni * 16 + lane15;
        C[(size_t)m * 768 + n] = acc[mi][ni][r] + bias[n];
      }
    }
  }
}

// ---------------- attention v4: block-coop LDS K/V pipeline ----------------
// Block decode: xcd=b&7, slot=b>>3 (408 = 24 groups * 17); group = 4 bh.
//  r 0..15: i=r>>2 -> bh, sub=r&3: sub<3 FULL (rows 128+sub*128, nk=528),
//           sub==3 LIGHT (rows 0-127, nk=128).  r==16: TAIL (4 bh, rows 512-527).
__global__ __launch_bounds__(256, 3) void k_attn(ushort_t* __restrict__ Q,
                                                 const ushort_t* __restrict__ K,
                                                 const ushort_t* __restrict__ Vt) {
  __shared__ ushort_t Ksh[2][32 * 64];
  __shared__ ushort_t Vsh[2][64 * 32];
  const int tid = threadIdx.x;
  const int wv = tid >> 6, lane = tid & 63;
  const int lane15 = lane & 15, quad = lane >> 4;
  const int b = blockIdx.x, xcd = b & 7, slot = b >> 3;
  const int g = slot / 17, r = slot - g * 17;
  const int bh0 = (xcd * 24 + g) * 4;

  bf16x8 ones;
#pragma unroll
  for (int i = 0; i < 8; i++) ones[i] = (short)0x3F80;

  const int krp = ((lane15 >> 2) << 3) + (lane15 & 3);

  if (r < 16) {  // ---- FULL / LIGHT: block-coop, LDS-shared K/V ----
    const int sub = r & 3;
    const int bh = bh0 + (r >> 2);
    const bool light = (sub == 3);
    const int rows0 = light ? (wv * 32) : (128 + sub * 128 + wv * 32);
    const int nch = light ? 4 : 17;

    ushort_t* Qb = Q + (size_t)bh * LQ * DH;
    const ushort_t* Kbh = K + (size_t)bh * LQ * DH;
    const ushort_t* Vbh = Vt + (size_t)bh * DH * VTP;

    bf16x8 aq[2][2];
#pragma unroll
    for (int mt = 0; mt < 2; mt++)
#pragma unroll
      for (int h = 0; h < 2; h++)
        aq[mt][h] = *(const bf16x8*)&Qb[(size_t)(rows0 + mt * 16 + lane15) * DH + h * 32 + quad * 8];

    f32x4 o[2][4], sm[2];
#pragma unroll
    for (int mt = 0; mt < 2; mt++) {
      sm[mt] = (f32x4)0.0f;
#pragma unroll
      for (int dt = 0; dt < 4; dt++) o[mt][dt] = (f32x4)0.0f;
    }

    auto stageKV = [&](int buf, int kc) {
      {
        int rr = tid >> 3, u = tid & 7;
        const ushort_t* src = Kbh + (size_t)(kc + rr) * DH + ((u ^ swzK(rr)) << 3);
        __builtin_amdgcn_global_load_lds((gp1_t)src, (lp3_t)&Ksh[buf][(wv * 8) * 64], 16, 0, 0);
      }
      {
        int d = tid >> 2, cc = tid & 3;
        const ushort_t* src = Vbh + (size_t)d * VTP + kc + ((cc ^ swzV(d)) << 3);
        __builtin_amdgcn_global_load_lds((gp1_t)src, (lp3_t)&Vsh[buf][(wv * 16) * 32], 16, 0, 0);
      }
    };

    stageKV(0, 0);
    for (int c = 0; c < nch; c++) {
      __syncthreads();                       // buf c&1 staged; prior reads done
      if (c + 1 < nch) stageKV((c + 1) & 1, (c + 1) * 32);
      const int buf = c & 1;
      bf16x8 kf[2][2], vf[4];
#pragma unroll
      for (int ss = 0; ss < 2; ss++) {
        int kr = krp + ss * 4;
#pragma unroll
        for (int h = 0; h < 2; h++)
          kf[ss][h] = *(const bf16x8*)&Ksh[buf][kr * 64 + (((h * 4 + quad) ^ swzK(kr)) << 3)];
      }
#pragma unroll
      for (int dt = 0; dt < 4; dt++) {
        int d = dt * 16 + lane15;
        vf[dt] = *(const bf16x8*)&Vsh[buf][d * 32 + ((quad ^ swzV(d)) << 3)];
      }
      const bool maskl = (c == 16) && (quad >= 2);
#pragma unroll
      for (int mt = 0; mt < 2; mt++) {
        f32x4 c0 = (f32x4)0.0f, c1 = (f32x4)0.0f;
        c0 = MFMA(kf[0][0], aq[mt][0], c0);
        c0 = MFMA(kf[0][1], aq[mt][1], c0);
        c1 = MFMA(kf[1][0], aq[mt][0], c1);
        c1 = MFMA(kf[1][1], aq[mt][1], c1);
        u32 pw[8];
#pragma unroll
        for (int rr = 0; rr < 4; rr++) {
          float a0 = maskl ? -30.0f : c0[rr];
          float a1 = maskl ? -30.0f : c1[rr];
          pw[rr]     = __float_as_uint(exp2f(a0)) + 0x8000u;
          pw[4 + rr] = __float_as_uint(exp2f(a1)) + 0x8000u;
        }
        union { bf16x8 v; u32 w[4]; } pb;
        pb.w[0] = pack2(pw[1], pw[0]);
        pb.w[1] = pack2(pw[3], pw[2]);
        pb.w[2] = pack2(pw[5], pw[4]);
        pb.w[3] = pack2(pw[7], pw[6]);
        sm[mt] = MFMA(ones, pb.v, sm[mt]);
#pragma unroll
        for (int dt = 0; dt < 4; dt++)
          o[mt][dt] = MFMA(vf[dt], pb.v, o[mt][dt]);
      }
    }

#pragma unroll
    for (int mt = 0; mt < 2; mt++) {
      float inv = 1.0f / sm[mt][0];
      ushort_t* orow = &Qb[(size_t)(rows0 + mt * 16 + lane15) * DH];
#pragma unroll
      for (int dt = 0; dt < 4; dt++) {
        u32 r0 = __float_as_uint(o[mt][dt][0] * inv) + 0x8000u;
        u32 r1 = __float_as_uint(o[mt][dt][1] * inv) + 0x8000u;
        u32 r2 = __float_as_uint(o[mt][dt][2] * inv) + 0x8000u;
        u32 r3 = __float_as_uint(o[mt][dt][3] * inv) + 0x8000u;
        uint2 st;
        st.x = pack2(r1, r0);
        st.y = pack2(r3, r2);
        *(uint2*)&orow[dt * 16 + quad * 4] = st;
      }
    }
  } else {  // ---- TAIL: 4 waves, each bh0+wv rows 512-527, register path ----
    const int bh = bh0 + wv;
    ushort_t* Qb = Q + (size_t)bh * LQ * DH;
    const ushort_t* Kbh = K + (size_t)bh * LQ * DH;
    const ushort_t* Vbh = Vt + (size_t)bh * DH * VTP;

    bf16x8 aq[2];
#pragma unroll
    for (int h = 0; h < 2; h++)
      aq[h] = *(const bf16x8*)&Qb[(size_t)(512 + lane15) * DH + h * 32 + quad * 8];

    f32x4 o[4], sm = (f32x4)0.0f;
#pragma unroll
    for (int dt = 0; dt < 4; dt++) o[dt] = (f32x4)0.0f;

    const ushort_t* kbase = Kbh + (size_t)krp * DH + quad * 8;
    const ushort_t* vbase = Vbh + (size_t)lane15 * VTP + quad * 8;

    for (int kc = 0; kc < 528; kc += 32) {
      bf16x8 kf[2][2], vf[4];
#pragma unroll
      for (int ss = 0; ss < 2; ss++) {
        const ushort_t* p = kbase + (size_t)(kc + ss * 4) * DH;
        kf[ss][0] = *(const bf16x8*)&p[0];
        kf[ss][1] = *(const bf16x8*)&p[32];
      }
#pragma unroll
      for (int dt = 0; dt < 4; dt++)
        vf[dt] = *(const bf16x8*)&vbase[(size_t)dt * 16 * VTP + kc];

      f32x4 c0 = (f32x4)0.0f, c1 = (f32x4)0.0f;
      c0 = MFMA(kf[0][0], aq[0], c0);
      c0 = MFMA(kf[0][1], aq[1], c0);
      c1 = MFMA(kf[1][0], aq[0], c1);
      c1 = MFMA(kf[1][1], aq[1], c1);
      const bool maskl = (kc == 512) && (quad >= 2);
      u32 pw[8];
#pragma unroll
      for (int rr = 0; rr < 4; rr++) {
        float a0 = maskl ? -30.0f : c0[rr];
        float a1 = maskl ? -30.0f : c1[rr];
        pw[rr]     = __float_as_uint(exp2f(a0)) + 0x8000u;
        pw[4 + rr] = __float_as_uint(exp2f(a1)) + 0x8000u;
      }
      union { bf16x8 v; u32 w[4]; } pb;
      pb.w[0] = pack2(pw[1], pw[0]);
      pb.w[1] = pack2(pw[3], pw[2]);
      pb.w[2] = pack2(pw[5], pw[4]);
      pb.w[3] = pack2(pw[7], pw[6]);
      sm = MFMA(ones, pb.v, sm);
#pragma unroll
      for (int dt = 0; dt < 4; dt++)
        o[dt] = MFMA(vf[dt], pb.v, o[dt]);
    }

    float inv = 1.0f / sm[0];
    ushort_t* orow = &Qb[(size_t)(512 + lane15) * DH];
#pragma unroll
    for (int dt = 0; dt < 4; dt++) {
      u32 r0 = __float_as_uint(o[dt][0] * inv) + 0x8000u;
      u32 r1 = __float_as_uint(o[dt][1] * inv) + 0x8000u;
      u32 r2 = __float_as_uint(o[dt][2] * inv) + 0x8000u;
      u32 r3 = __float_as_uint(o[dt][3] * inv) + 0x8000u;
      uint2 st;
      st.x = pack2(r1, r0);
      st.y = pack2(r3, r2);
      *(uint2*)&orow[dt * 16 + quad * 4] = st;
    }
  }
}

// ---------------- launch ----------------
extern "C" void kernel_launch(void* const* d_in, const int* in_sizes, int n_in,
                              void* d_out, int out_size, void* d_ws, size_t ws_size,
                              hipStream_t stream) {
  const float* x = (const float*)d_in[0];
  const float* Wq = (const float*)d_in[1];
  const float* Wk = (const float*)d_in[2];
  const float* Wv = (const float*)d_in[3];
  const float* Wp = (const float*)d_in[4];
  const float* bp = (const float*)d_in[5];
  float* out = (float*)d_out;

  char* ws = (char*)d_ws;
  size_t off = 0;
  auto alloc = [&](size_t bytes) {
    void* p = ws + off;
    off += (bytes + 255) & ~(size_t)255;
    return p;
  };
  ushort_t* xb = (ushort_t*)alloc((size_t)MTOK * DIM * 2);
  ushort_t* wtq = (ushort_t*)alloc((size_t)DIM * DIM * 2);
  ushort_t* wtk = (ushort_t*)alloc((size_t)DIM * DIM * 2);
  ushort_t* wtv = (ushort_t*)alloc((size_t)DIM * DIM * 2);
  ushort_t* wtp = (ushort_t*)alloc((size_t)DIM * DIM * 2);
  ushort_t* Qb = (ushort_t*)alloc((size_t)MTOK * DIM * 2);   // Q, then attn out in-place
  ushort_t* Kb = (ushort_t*)alloc((size_t)MTOK * DIM * 2);
  ushort_t* Vtb = (ushort_t*)alloc((size_t)BATCH * NH * DH * VTP * 2);
  (void)ws_size; (void)in_sizes; (void)n_in; (void)out_size;

  k_convert_x<<<25344, 256, 0, stream>>>(x, xb);
  k_convert_w<<<dim3(12, 12, 4), 256, 0, stream>>>(Wq, Wk, Wv, Wp, wtq, wtk, wtv, wtp);
  k_gemm_qkv<<<4752, 256, 0, stream>>>(xb, wtq, wtk, wtv, Qb, Kb, Vtb);
  k_attn<<<3264, 256, 0, stream>>>(Qb, Kb, Vtb);
  k_gemm_out<<<1584, 256, 0, stream>>>(Qb, wtp, out, bp);
}

// Round 5
// 504.625 us; speedup vs baseline: 2.1770x; 1.0386x over previous
//
#include <hip/hip_runtime.h>
#include <stdint.h>

typedef __attribute__((ext_vector_type(8))) short bf16x8;
typedef __attribute__((ext_vector_type(4))) float f32x4;
typedef unsigned short ushort_t;
typedef unsigned int u32;
typedef const __attribute__((address_space(1))) u32* gp1_t;
typedef __attribute__((address_space(3))) u32* lp3_t;

#define MFMA(a,b,c) __builtin_amdgcn_mfma_f32_16x16x32_bf16((a),(b),(c),0,0,0)

static constexpr int BATCH = 64, LQ = 528, DIM = 768, NH = 12, DH = 64;
static constexpr int MTOK = BATCH * LQ;   // 33792
static constexpr int VTP  = 544;          // padded Vt row stride (keys)
// scale * log2(e): folded into Q so softmax is a bare exp2
static constexpr float QSCALE = (float)(0.03608439182435161 * 1.4426950408889634);

__device__ __forceinline__ ushort_t f2bf(float f) {
  u32 u = __float_as_uint(f);
  u = (u + 0x7fffu + ((u >> 16) & 1u)) >> 16;
  return (ushort_t)u;
}
__device__ __forceinline__ u32 pack2(u32 xr, u32 yr) {  // lo=yr.bf16, hi=xr.bf16
  return __builtin_amdgcn_perm(xr, yr, 0x07060302u);
}
__device__ __forceinline__ int swzK(int r) { return (r & 3) | (((r >> 3) & 1) << 2); }
__device__ __forceinline__ int swzV(int d) { return (d >> 2) & 3; }

// ---------------- conversion kernels ----------------
__global__ __launch_bounds__(256) void k_convert_x(const float* __restrict__ x,
                                                   ushort_t* __restrict__ xb) {
  int i = blockIdx.x * 256 + threadIdx.x;
  float4 v = ((const float4*)x)[i];
  ushort4 o;
  o.x = f2bf(v.x); o.y = f2bf(v.y); o.z = f2bf(v.z); o.w = f2bf(v.w);
  ((ushort4*)xb)[i] = o;
}

// LDS-tiled transpose: W[k][n] f32 -> Wt[n][k] bf16, coalesced both sides
__global__ __launch_bounds__(256) void k_convert_w(
    const float* __restrict__ w0, const float* __restrict__ w1,
    const float* __restrict__ w2, const float* __restrict__ w3,
    ushort_t* __restrict__ o0, ushort_t* __restrict__ o1,
    ushort_t* __restrict__ o2, ushort_t* __restrict__ o3) {
  __shared__ ushort_t t[64][65];
  int mid = blockIdx.z;
  const float* src = (mid == 0) ? w0 : (mid == 1) ? w1 : (mid == 2) ? w2 : w3;
  ushort_t* dst = (mid == 0) ? o0 : (mid == 1) ? o1 : (mid == 2) ? o2 : o3;
  int k0 = blockIdx.x * 64, n0 = blockIdx.y * 64;
  int c = threadIdx.x & 63, rr = threadIdx.x >> 6;
#pragma unroll
  for (int p = 0; p < 16; p++) {
    int r = p * 4 + rr;
    t[c][r] = f2bf(src[(size_t)(k0 + r) * DIM + n0 + c]);
  }
  __syncthreads();
#pragma unroll
  for (int p = 0; p < 16; p++) {
    int r = p * 4 + rr;
    dst[(size_t)(n0 + r) * DIM + k0 + c] = t[r][c];
  }
}

// ---------------- fused QKV GEMM, 128x128 tile, BK=64, XOR-swizzled LDS -------
// LDS layout: chunk c (8 elems) of local row r stored at position c^(r&7).
// Row stride 128 B = full bank cycle; frag ds_read_b128 is 2-way max (free).
__global__ __launch_bounds__(256, 2) void k_gemm_qkv(
    const ushort_t* __restrict__ A, const ushort_t* __restrict__ wq,
    const ushort_t* __restrict__ wk, const ushort_t* __restrict__ wv,
    ushort_t* __restrict__ Qb, ushort_t* __restrict__ Kb, ushort_t* __restrict__ Vtb) {
  // XCD swizzle: 4752 = 8 * (33 mT * 18 nt); same-mT blocks consecutive per XCD
  const int id = blockIdx.x, xcd = id & 7, s = id >> 3;
  const int mT = xcd * 33 + s / 18, t = s % 18, w = t / 6, nT = t % 6;
  const ushort_t* Bt = (w == 0) ? wq : (w == 1) ? wk : wv;

  __shared__ ushort_t at[128 * 64];
  __shared__ ushort_t bt[128 * 64];
  const int tid = threadIdx.x;
  const int wv_ = tid >> 6, lane = tid & 63;
  const int lane15 = lane & 15, quad = lane >> 4;
  const int mw = (wv_ & 1) * 64, nw = (wv_ >> 1) * 64;

  f32x4 acc[4][4];
#pragma unroll
  for (int i = 0; i < 4; i++)
#pragma unroll
    for (int j = 0; j < 4; j++) acc[i][j] = (f32x4)0.0f;

  const int lrow = lane >> 3;    // 0..7
  const int lchunk = lane & 7;   // 0..7

  for (int kb = 0; kb < 768; kb += 64) {
#pragma unroll
    for (int i = 0; i < 4; i++) {
      int r0 = wv_ * 32 + i * 8;
      int lr = r0 + lrow;
      size_t off = (size_t)(mT * 128 + lr) * 768 + kb + ((lchunk ^ (lr & 7)) << 3);
      __builtin_amdgcn_global_load_lds((gp1_t)(A + off), (lp3_t)(&at[r0 * 64]), 16, 0, 0);
    }
#pragma unroll
    for (int i = 0; i < 4; i++) {
      int r0 = wv_ * 32 + i * 8;
      int lr = r0 + lrow;
      size_t off = (size_t)(nT * 128 + lr) * 768 + kb + ((lchunk ^ (lr & 7)) << 3);
      __builtin_amdgcn_global_load_lds((gp1_t)(Bt + off), (lp3_t)(&bt[r0 * 64]), 16, 0, 0);
    }
    __syncthreads();
#pragma unroll
    for (int h = 0; h < 2; h++) {
      bf16x8 af[4], bf[4];
#pragma unroll
      for (int mi = 0; mi < 4; mi++) {
        int row = mw + mi * 16 + lane15;
        af[mi] = *(const bf16x8*)&at[row * 64 + (((h * 4 + quad) ^ (row & 7)) << 3)];
      }
#pragma unroll
      for (int ni = 0; ni < 4; ni++) {
        int row = nw + ni * 16 + lane15;
        bf[ni] = *(const bf16x8*)&bt[row * 64 + (((h * 4 + quad) ^ (row & 7)) << 3)];
      }
#pragma unroll
      for (int mi = 0; mi < 4; mi++)
#pragma unroll
        for (int ni = 0; ni < 4; ni++)
          acc[mi][ni] = MFMA(af[mi], bf[ni], acc[mi][ni]);
    }
    __syncthreads();
  }

  const float scale = (w == 0) ? QSCALE : 1.0f;
  ushort_t* Cqk = (w == 0) ? Qb : Kb;
#pragma unroll
  for (int mi = 0; mi < 4; mi++) {
#pragma unroll
    for (int r = 0; r < 4; r++) {
      int m = mT * 128 + mw + mi * 16 + quad * 4 + r;
      int b = m / 528, lt = m - b * 528;
#pragma unroll
      for (int ni = 0; ni < 4; ni++) {
        int n = nT * 128 + nw + ni * 16 + lane15;
        float v = acc[mi][ni][r];
        if (w < 2) {
          Cqk[(((size_t)(b * 12 + (n >> 6)) * 528 + lt) << 6) + (n & 63)] = f2bf(v * scale);
        } else {
          Vtb[((size_t)(b * 12 + (n >> 6)) * 64 + (n & 63)) * VTP + lt] = f2bf(v);
        }
      }
    }
  }
}

// ---------------- out-proj GEMM, BK=64, swizzled (A in (b,h,l,d) layout) ------
__global__ __launch_bounds__(256, 2) void k_gemm_out(const ushort_t* __restrict__ A,
                                                     const ushort_t* __restrict__ Bt,
                                                     float* __restrict__ C,
                                                     const float* __restrict__ bias) {
  const int id = blockIdx.x, xcd = id & 7, s = id >> 3;  // 1584 = 8*(33*6)
  const int mT = xcd * 33 + s / 6, nT = s % 6;

  __shared__ ushort_t at[128 * 64];
  __shared__ ushort_t bt[128 * 64];
  const int tid = threadIdx.x;
  const int wv_ = tid >> 6, lane = tid & 63;
  const int lane15 = lane & 15, quad = lane >> 4;
  const int mw = (wv_ & 1) * 64, nw = (wv_ >> 1) * 64;

  f32x4 acc[4][4];
#pragma unroll
  for (int i = 0; i < 4; i++)
#pragma unroll
    for (int j = 0; j < 4; j++) acc[i][j] = (f32x4)0.0f;

  const int lrow = lane >> 3;
  const int lchunk = lane & 7;

  for (int kb = 0; kb < 768; kb += 64) {
#pragma unroll
    for (int i = 0; i < 4; i++) {
      int r0 = wv_ * 32 + i * 8;
      int lr = r0 + lrow;
      int grow = mT * 128 + lr;
      int gk = kb + ((lchunk ^ (lr & 7)) << 3);
      int b = grow / 528, ltk = grow - b * 528;
      size_t off = (((size_t)(b * 12 + (gk >> 6)) * 528 + ltk) << 6) + (gk & 63);
      __builtin_amdgcn_global_load_lds((gp1_t)(A + off), (lp3_t)(&at[r0 * 64]), 16, 0, 0);
    }
#pragma unroll
    for (int i = 0; i < 4; i++) {
      int r0 = wv_ * 32 + i * 8;
      int lr = r0 + lrow;
      size_t off = (size_t)(nT * 128 + lr) * 768 + kb + ((lchunk ^ (lr & 7)) << 3);
      __builtin_amdgcn_global_load_lds((gp1_t)(Bt + off), (lp3_t)(&bt[r0 * 64]), 16, 0, 0);
    }
    __syncthreads();
#pragma unroll
    for (int h = 0; h < 2; h++) {
      bf16x8 af[4], bf[4];
#pragma unroll
      for (int mi = 0; mi < 4; mi++) {
        int row = mw + mi * 16 + lane15;
        af[mi] = *(const bf16x8*)&at[row * 64 + (((h * 4 + quad) ^ (row & 7)) << 3)];
      }
#pragma unroll
      for (int ni = 0; ni < 4; ni++) {
        int row = nw + ni * 16 + lane15;
        bf[ni] = *(const bf16x8*)&bt[row * 64 + (((h * 4 + quad) ^ (row & 7)) << 3)];
      }
#pragma unroll
      for (int mi = 0; mi < 4; mi++)
#pragma unroll
        for (int ni = 0; ni < 4; ni++)
          acc[mi][ni] = MFMA(af[mi], bf[ni], acc[mi][ni]);
    }
    __syncthreads();
  }

#pragma unroll
  for (int mi = 0; mi < 4; mi++) {
#pragma unroll
    for (int r = 0; r < 4; r++) {
      int m = mT * 128 + mw + mi * 16 + quad * 4 + r;
#pragma unroll
      for (int ni = 0; ni < 4; ni++) {
        int n = nT * 128 + nw + ni * 16 + lane15;
        C[(size_t)m * 768 + n] = acc[mi][ni][r] + bias[n];
      }
    }
  }
}

// ---------------- attention v4: block-coop LDS K/V pipeline ----------------
__global__ __launch_bounds__(256, 3) void k_attn(ushort_t* __restrict__ Q,
                                                 const ushort_t* __restrict__ K,
                                                 const ushort_t* __restrict__ Vt) {
  __shared__ ushort_t Ksh[2][32 * 64];
  __shared__ ushort_t Vsh[2][64 * 32];
  const int tid = threadIdx.x;
  const int wv = tid >> 6, lane = tid & 63;
  const int lane15 = lane & 15, quad = lane >> 4;
  const int b = blockIdx.x, xcd = b & 7, slot = b >> 3;
  const int g = slot / 17, r = slot - g * 17;
  const int bh0 = (xcd * 24 + g) * 4;

  bf16x8 ones;
#pragma unroll
  for (int i = 0; i < 8; i++) ones[i] = (short)0x3F80;

  const int krp = ((lane15 >> 2) << 3) + (lane15 & 3);

  if (r < 16) {  // ---- FULL / LIGHT: block-coop, LDS-shared K/V ----
    const int sub = r & 3;
    const int bh = bh0 + (r >> 2);
    const bool light = (sub == 3);
    const int rows0 = light ? (wv * 32) : (128 + sub * 128 + wv * 32);
    const int nch = light ? 4 : 17;

    ushort_t* Qb = Q + (size_t)bh * LQ * DH;
    const ushort_t* Kbh = K + (size_t)bh * LQ * DH;
    const ushort_t* Vbh = Vt + (size_t)bh * DH * VTP;

    bf16x8 aq[2][2];
#pragma unroll
    for (int mt = 0; mt < 2; mt++)
#pragma unroll
      for (int h = 0; h < 2; h++)
        aq[mt][h] = *(const bf16x8*)&Qb[(size_t)(rows0 + mt * 16 + lane15) * DH + h * 32 + quad * 8];

    f32x4 o[2][4], sm[2];
#pragma unroll
    for (int mt = 0; mt < 2; mt++) {
      sm[mt] = (f32x4)0.0f;
#pragma unroll
      for (int dt = 0; dt < 4; dt++) o[mt][dt] = (f32x4)0.0f;
    }

    auto stageKV = [&](int buf, int kc) {
      {
        int rr = tid >> 3, u = tid & 7;
        const ushort_t* src = Kbh + (size_t)(kc + rr) * DH + ((u ^ swzK(rr)) << 3);
        __builtin_amdgcn_global_load_lds((gp1_t)src, (lp3_t)&Ksh[buf][(wv * 8) * 64], 16, 0, 0);
      }
      {
        int d = tid >> 2, cc = tid & 3;
        const ushort_t* src = Vbh + (size_t)d * VTP + kc + ((cc ^ swzV(d)) << 3);
        __builtin_amdgcn_global_load_lds((gp1_t)src, (lp3_t)&Vsh[buf][(wv * 16) * 32], 16, 0, 0);
      }
    };

    stageKV(0, 0);
    for (int c = 0; c < nch; c++) {
      __syncthreads();
      if (c + 1 < nch) stageKV((c + 1) & 1, (c + 1) * 32);
      const int buf = c & 1;
      bf16x8 kf[2][2], vf[4];
#pragma unroll
      for (int ss = 0; ss < 2; ss++) {
        int kr = krp + ss * 4;
#pragma unroll
        for (int h = 0; h < 2; h++)
          kf[ss][h] = *(const bf16x8*)&Ksh[buf][kr * 64 + (((h * 4 + quad) ^ swzK(kr)) << 3)];
      }
#pragma unroll
      for (int dt = 0; dt < 4; dt++) {
        int d = dt * 16 + lane15;
        vf[dt] = *(const bf16x8*)&Vsh[buf][d * 32 + ((quad ^ swzV(d)) << 3)];
      }
      const bool maskl = (c == 16) && (quad >= 2);
#pragma unroll
      for (int mt = 0; mt < 2; mt++) {
        f32x4 c0 = (f32x4)0.0f, c1 = (f32x4)0.0f;
        c0 = MFMA(kf[0][0], aq[mt][0], c0);
        c0 = MFMA(kf[0][1], aq[mt][1], c0);
        c1 = MFMA(kf[1][0], aq[mt][0], c1);
        c1 = MFMA(kf[1][1], aq[mt][1], c1);
        u32 pw[8];
#pragma unroll
        for (int rr = 0; rr < 4; rr++) {
          float a0 = maskl ? -30.0f : c0[rr];
          float a1 = maskl ? -30.0f : c1[rr];
          pw[rr]     = __float_as_uint(exp2f(a0)) + 0x8000u;
          pw[4 + rr] = __float_as_uint(exp2f(a1)) + 0x8000u;
        }
        union { bf16x8 v; u32 w[4]; } pb;
        pb.w[0] = pack2(pw[1], pw[0]);
        pb.w[1] = pack2(pw[3], pw[2]);
        pb.w[2] = pack2(pw[5], pw[4]);
        pb.w[3] = pack2(pw[7], pw[6]);
        sm[mt] = MFMA(ones, pb.v, sm[mt]);
#pragma unroll
        for (int dt = 0; dt < 4; dt++)
          o[mt][dt] = MFMA(vf[dt], pb.v, o[mt][dt]);
      }
    }

#pragma unroll
    for (int mt = 0; mt < 2; mt++) {
      float inv = 1.0f / sm[mt][0];
      ushort_t* orow = &Qb[(size_t)(rows0 + mt * 16 + lane15) * DH];
#pragma unroll
      for (int dt = 0; dt < 4; dt++) {
        u32 r0 = __float_as_uint(o[mt][dt][0] * inv) + 0x8000u;
        u32 r1 = __float_as_uint(o[mt][dt][1] * inv) + 0x8000u;
        u32 r2 = __float_as_uint(o[mt][dt][2] * inv) + 0x8000u;
        u32 r3 = __float_as_uint(o[mt][dt][3] * inv) + 0x8000u;
        uint2 st;
        st.x = pack2(r1, r0);
        st.y = pack2(r3, r2);
        *(uint2*)&orow[dt * 16 + quad * 4] = st;
      }
    }
  } else {  // ---- TAIL: 4 waves, each bh0+wv rows 512-527, register path ----
    const int bh = bh0 + wv;
    ushort_t* Qb = Q + (size_t)bh * LQ * DH;
    const ushort_t* Kbh = K + (size_t)bh * LQ * DH;
    const ushort_t* Vbh = Vt + (size_t)bh * DH * VTP;

    bf16x8 aq[2];
#pragma unroll
    for (int h = 0; h < 2; h++)
      aq[h] = *(const bf16x8*)&Qb[(size_t)(512 + lane15) * DH + h * 32 + quad * 8];

    f32x4 o[4], sm = (f32x4)0.0f;
#pragma unroll
    for (int dt = 0; dt < 4; dt++) o[dt] = (f32x4)0.0f;

    const ushort_t* kbase = Kbh + (size_t)krp * DH + quad * 8;
    const ushort_t* vbase = Vbh + (size_t)lane15 * VTP + quad * 8;

    for (int kc = 0; kc < 528; kc += 32) {
      bf16x8 kf[2][2], vf[4];
#pragma unroll
      for (int ss = 0; ss < 2; ss++) {
        const ushort_t* p = kbase + (size_t)(kc + ss * 4) * DH;
        kf[ss][0] = *(const bf16x8*)&p[0];
        kf[ss][1] = *(const bf16x8*)&p[32];
      }
#pragma unroll
      for (int dt = 0; dt < 4; dt++)
        vf[dt] = *(const bf16x8*)&vbase[(size_t)dt * 16 * VTP + kc];

      f32x4 c0 = (f32x4)0.0f, c1 = (f32x4)0.0f;
      c0 = MFMA(kf[0][0], aq[0], c0);
      c0 = MFMA(kf[0][1], aq[1], c0);
      c1 = MFMA(kf[1][0], aq[0], c1);
      c1 = MFMA(kf[1][1], aq[1], c1);
      const bool maskl = (kc == 512) && (quad >= 2);
      u32 pw[8];
#pragma unroll
      for (int rr = 0; rr < 4; rr++) {
        float a0 = maskl ? -30.0f : c0[rr];
        float a1 = maskl ? -30.0f : c1[rr];
        pw[rr]     = __float_as_uint(exp2f(a0)) + 0x8000u;
        pw[4 + rr] = __float_as_uint(exp2f(a1)) + 0x8000u;
      }
      union { bf16x8 v; u32 w[4]; } pb;
      pb.w[0] = pack2(pw[1], pw[0]);
      pb.w[1] = pack2(pw[3], pw[2]);
      pb.w[2] = pack2(pw[5], pw[4]);
      pb.w[3] = pack2(pw[7], pw[6]);
      sm = MFMA(ones, pb.v, sm);
#pragma unroll
      for (int dt = 0; dt < 4; dt++)
        o[dt] = MFMA(vf[dt], pb.v, o[dt]);
    }

    float inv = 1.0f / sm[0];
    ushort_t* orow = &Qb[(size_t)(512 + lane15) * DH];
#pragma unroll
    for (int dt = 0; dt < 4; dt++) {
      u32 r0 = __float_as_uint(o[dt][0] * inv) + 0x8000u;
      u32 r1 = __float_as_uint(o[dt][1] * inv) + 0x8000u;
      u32 r2 = __float_as_uint(o[dt][2] * inv) + 0x8000u;
      u32 r3 = __float_as_uint(o[dt][3] * inv) + 0x8000u;
      uint2 st;
      st.x = pack2(r1, r0);
      st.y = pack2(r3, r2);
      *(uint2*)&orow[dt * 16 + quad * 4] = st;
    }
  }
}

// ---------------- launch ----------------
extern "C" void kernel_launch(void* const* d_in, const int* in_sizes, int n_in,
                              void* d_out, int out_size, void* d_ws, size_t ws_size,
                              hipStream_t stream) {
  const float* x = (const float*)d_in[0];
  const float* Wq = (const float*)d_in[1];
  const float* Wk = (const float*)d_in[2];
  const float* Wv = (const float*)d_in[3];
  const float* Wp = (const float*)d_in[4];
  const float* bp = (const float*)d_in[5];
  float* out = (float*)d_out;

  char* ws = (char*)d_ws;
  size_t off = 0;
  auto alloc = [&](size_t bytes) {
    void* p = ws + off;
    off += (bytes + 255) & ~(size_t)255;
    return p;
  };
  ushort_t* xb = (ushort_t*)alloc((size_t)MTOK * DIM * 2);
  ushort_t* wtq = (ushort_t*)alloc((size_t)DIM * DIM * 2);
  ushort_t* wtk = (ushort_t*)alloc((size_t)DIM * DIM * 2);
  ushort_t* wtv = (ushort_t*)alloc((size_t)DIM * DIM * 2);
  ushort_t* wtp = (ushort_t*)alloc((size_t)DIM * DIM * 2);
  ushort_t* Qb = (ushort_t*)alloc((size_t)MTOK * DIM * 2);   // Q, then attn out in-place
  ushort_t* Kb = (ushort_t*)alloc((size_t)MTOK * DIM * 2);
  ushort_t* Vtb = (ushort_t*)alloc((size_t)BATCH * NH * DH * VTP * 2);
  (void)ws_size; (void)in_sizes; (void)n_in; (void)out_size;

  k_convert_x<<<25344, 256, 0, stream>>>(x, xb);
  k_convert_w<<<dim3(12, 12, 4), 256, 0, stream>>>(Wq, Wk, Wv, Wp, wtq, wtk, wtv, wtp);
  k_gemm_qkv<<<4752, 256, 0, stream>>>(xb, wtq, wtk, wtv, Qb, Kb, Vtb);
  k_attn<<<3264, 256, 0, stream>>>(Qb, Kb, Vtb);
  k_gemm_out<<<1584, 256, 0, stream>>>(Qb, wtp, out, bp);
}